// Round 6
// baseline (141.868 us; speedup 1.0000x reference)
//
#include <hip/hip_runtime.h>
#include <hip/hip_bf16.h>

#define KTOT   25088          // 2 * 256 * 49
#define HALF_K 12544
#define HID    512
#define SPLITK 28
#define KCHUNK (KTOT/SPLITK)  // 896
#define KSTEPS (KCHUNK/32)    // 28

typedef __attribute__((ext_vector_type(8))) short short8;
typedef __attribute__((ext_vector_type(4))) float f32x4;

__device__ __forceinline__ unsigned short f2bf(float x) {
  __hip_bfloat16 h = __float2bfloat16(x);
  return *reinterpret_cast<unsigned short*>(&h);
}
__device__ __forceinline__ float bf2f(unsigned short u) {
  return __uint_as_float((unsigned)u << 16);
}

// ---------- feats [C,H,W] fp32 -> ft bf16 [map][y*32+x][c] ----------
__global__ __launch_bounds__(256) void k_tfeat(const float* __restrict__ f1,
                                               const float* __restrict__ f2,
                                               __hip_bfloat16* __restrict__ ft) {
  __shared__ float tile[64][65];
  const int ct = blockIdx.x, yxt = blockIdx.y, map = blockIdx.z;
  const float* src = map ? f2 : f1;
  const int t = threadIdx.x, t4 = t >> 6, tl = t & 63;
#pragma unroll
  for (int pass = 0; pass < 16; ++pass) {
    int cl = pass * 4 + t4;
    tile[cl][tl] = src[(ct * 64 + cl) * 1024 + yxt * 64 + tl];
  }
  __syncthreads();
#pragma unroll
  for (int pass = 0; pass < 16; ++pass) {
    int yl = pass * 4 + t4;
    ft[(size_t)map * 262144 + (size_t)(yxt * 64 + yl) * 256 + ct * 64 + tl] =
        __float2bfloat16(tile[tl][yl]);
  }
}

// ---------- W1 [25088][512] -> W1t bf16 [512][25088'] with k' = map*12544 + p*256 + c ----------
__global__ __launch_bounds__(256) void k_tw1(const float* __restrict__ W1,
                                             __hip_bfloat16* __restrict__ W1t) {
  __shared__ float tile[64][65];
  const int ct = blockIdx.x & 3, jt = blockIdx.x >> 2;
  const int p = blockIdx.y, map = blockIdx.z;
  const int t = threadIdx.x, t4 = t >> 6, tl = t & 63;
#pragma unroll
  for (int pass = 0; pass < 16; ++pass) {
    int cl = pass * 4 + t4;
    int c = ct * 64 + cl;
    size_t krow = (size_t)map * HALF_K + (size_t)c * 49 + p;
    tile[cl][tl] = W1[krow * HID + jt * 64 + tl];
  }
  __syncthreads();
#pragma unroll
  for (int pass = 0; pass < 16; ++pass) {
    int jl = pass * 4 + t4;
    int j = jt * 64 + jl;
    W1t[(size_t)j * KTOT + (size_t)map * HALF_K + p * 256 + ct * 64 + tl] =
        __float2bfloat16(tile[tl][jl]);
  }
}

// ---------- RoIAlign: 7-way bin split, b128 table reads, 32-bit saddr gathers ----------
// grid (N/2, 7); t: b=t>>7, map=(t>>6)&1, q=t&63 -> channels q*4..q*4+3
__global__ __launch_bounds__(256) void k_roi(const __hip_bfloat16* __restrict__ ft,
                                             const float* __restrict__ props,
                                             __hip_bfloat16* __restrict__ A) {
  __shared__ __align__(16) int2 tab[2][7 * 16];  // [box][bin_local*16 + sample*4 + corner]
  const int t = threadIdx.x;
  const int nb = blockIdx.x * 2;
  const int bin0 = blockIdx.y * 7;
  const float sc = 1.0f / 32.0f;
  for (int e = t; e < 224; e += 256) {
    int b = (e >= 112) ? 1 : 0;
    int ei = e - b * 112;
    int bin = bin0 + (ei >> 4), k = ei & 15;
    int s = k >> 2, corner = k & 3;
    int oyb = bin / 7, oxb = bin - oyb * 7;
    int py = oyb * 2 + (s >> 1), px = oxb * 2 + (s & 1);
    int n = nb + b;
    float bx1 = props[n * 4 + 0] * sc, by1 = props[n * 4 + 1] * sc;
    float bx2 = props[n * 4 + 2] * sc, by2 = props[n * 4 + 3] * sc;
    float bw = fmaxf(bx2 - bx1, 1.f) * (1.f / 7.f);
    float bh = fmaxf(by2 - by1, 1.f) * (1.f / 7.f);
    float oxf = bx1 + (float)(px >> 1) * bw + ((float)(px & 1) + 0.5f) * bw * 0.5f;
    float oyf = by1 + (float)(py >> 1) * bh + ((float)(py & 1) + 0.5f) * bh * 0.5f;
    float vx = (oxf >= -1.f && oxf <= 32.f) ? 1.f : 0.f;
    float vy = (oyf >= -1.f && oyf <= 32.f) ? 1.f : 0.f;
    float ocx = fminf(fmaxf(oxf, 0.f), 31.f);
    float ocy = fminf(fmaxf(oyf, 0.f), 31.f);
    int x0 = (int)ocx, y0 = (int)ocy;
    int x1 = min(x0 + 1, 31), y1 = min(y0 + 1, 31);
    float lx = ocx - (float)x0, ly = ocy - (float)y0;
    int cy = corner >> 1, cx = corner & 1;
    int yi = cy ? y1 : y0, xi = cx ? x1 : x0;
    float wyc = cy ? ly : (1.f - ly);
    float wxc = cx ? lx : (1.f - lx);
    float w = vx * vy * 0.25f * wyc * wxc;
    int2 v; v.x = (yi * 32 + xi) * 512; v.y = __float_as_int(w);
    tab[b][ei] = v;
  }
  __syncthreads();
  const int b = t >> 7, map = (t >> 6) & 1, q = t & 63;
  const char* fb = (const char*)ft;                       // SGPR base
  const unsigned qoff = (unsigned)(map * 524288 + q * 8); // per-lane constant
  const int n = nb + b;
  __hip_bfloat16* outp = A + (size_t)n * KTOT + map * HALF_K + q * 4;
  const int4* tb = (const int4*)&tab[b][0];
  for (int bl = 0; bl < 7; ++bl) {
    float a0 = 0.f, a1 = 0.f, a2 = 0.f, a3 = 0.f;
#pragma unroll
    for (int k2 = 0; k2 < 8; ++k2) {
      int4 ow = tb[bl * 8 + k2];
      unsigned o0 = qoff + (unsigned)ow.x;
      float w0 = __int_as_float(ow.y);
      ushort4 u0 = *(const ushort4*)(fb + o0);
      unsigned o1 = qoff + (unsigned)ow.z;
      float w1 = __int_as_float(ow.w);
      ushort4 u1 = *(const ushort4*)(fb + o1);
      a0 += w0 * bf2f(u0.x); a1 += w0 * bf2f(u0.y);
      a2 += w0 * bf2f(u0.z); a3 += w0 * bf2f(u0.w);
      a0 += w1 * bf2f(u1.x); a1 += w1 * bf2f(u1.y);
      a2 += w1 * bf2f(u1.z); a3 += w1 * bf2f(u1.w);
    }
    ushort4 o;
    o.x = f2bf(a0); o.y = f2bf(a1); o.z = f2bf(a2); o.w = f2bf(a3);
    *(ushort4*)(outp + (bin0 + bl) * 256) = o;
  }
}

// ---------- GEMM1: m97 structure, 128x128 tile, BK=32, 4 waves; bf16 parts [sp][col][row] ----------
__device__ __forceinline__ void gl_lds16(const __hip_bfloat16* g, __hip_bfloat16* l) {
  __builtin_amdgcn_global_load_lds((const __attribute__((address_space(1))) void*)g,
                                   (__attribute__((address_space(3))) void*)l, 16, 0, 0);
}

__global__ __launch_bounds__(256) void k_gemm1(const __hip_bfloat16* __restrict__ A,
                                               const __hip_bfloat16* __restrict__ Bt,
                                               __hip_bfloat16* __restrict__ parts, int M) {
  __shared__ __align__(16) __hip_bfloat16 As[128 * 32];
  __shared__ __align__(16) __hip_bfloat16 Bs[128 * 32];
  const int t = threadIdx.x;
  const int row0 = blockIdx.x * 128, col0 = blockIdx.y * 128;
  const size_t k0 = (size_t)blockIdx.z * KCHUNK;
  const int lr = t >> 2, lg = t & 3;
  const int sg = lg ^ ((lr >> 1) & 3);
  const __hip_bfloat16* ag0 = A  + (size_t)(row0 + lr) * KTOT + k0 + sg * 8;
  const __hip_bfloat16* ag1 = A  + (size_t)(row0 + 64 + lr) * KTOT + k0 + sg * 8;
  const __hip_bfloat16* bg0 = Bt + (size_t)(col0 + lr) * KTOT + k0 + sg * 8;
  const __hip_bfloat16* bg1 = Bt + (size_t)(col0 + 64 + lr) * KTOT + k0 + sg * 8;
  __hip_bfloat16* la0 = &As[t * 8];
  __hip_bfloat16* la1 = &As[2048 + t * 8];
  __hip_bfloat16* lb0 = &Bs[t * 8];
  __hip_bfloat16* lb1 = &Bs[2048 + t * 8];

  const int lane = t & 63, w = t >> 6;
  const int wr = (w >> 1) * 64, wc = (w & 1) * 64;
  const int r = lane & 15, g = lane >> 4;
  const int s = g ^ ((r >> 1) & 3);
  const int iab = (wr + r) * 32 + s * 8;
  const int ibb = (wc + r) * 32 + s * 8;

  f32x4 acc[4][4];
#pragma unroll
  for (int m = 0; m < 4; ++m)
#pragma unroll
    for (int n = 0; n < 4; ++n) acc[m][n] = (f32x4){0.f, 0.f, 0.f, 0.f};

  for (int kt = 0; kt < KSTEPS; ++kt) {
    gl_lds16(ag0, la0); gl_lds16(ag1, la1);
    gl_lds16(bg0, lb0); gl_lds16(bg1, lb1);
    ag0 += 32; ag1 += 32; bg0 += 32; bg1 += 32;
    __syncthreads();
    short8 af[4], bfr[4];
#pragma unroll
    for (int m = 0; m < 4; ++m) af[m] = *(const short8*)&As[iab + m * 512];
#pragma unroll
    for (int n = 0; n < 4; ++n) bfr[n] = *(const short8*)&Bs[ibb + n * 512];
#pragma unroll
    for (int m = 0; m < 4; ++m)
#pragma unroll
      for (int n = 0; n < 4; ++n)
        acc[m][n] = __builtin_amdgcn_mfma_f32_16x16x32_bf16(af[m], bfr[n], acc[m][n], 0, 0, 0);
    __syncthreads();
  }
  // parts layout: [sp][col][row] bf16; per (m,n) pack 4 consecutive rows -> ushort4
  unsigned short* P = (unsigned short*)parts + (size_t)blockIdx.z * ((size_t)HID * M);
#pragma unroll
  for (int m = 0; m < 4; ++m)
#pragma unroll
    for (int n = 0; n < 4; ++n) {
      int cc = col0 + wc + n * 16 + r;
      int rr0 = row0 + wr + m * 16 + g * 4;
      ushort4 o;
      o.x = f2bf(acc[m][n][0]); o.y = f2bf(acc[m][n][1]);
      o.z = f2bf(acc[m][n][2]); o.w = f2bf(acc[m][n][3]);
      *(ushort4*)(P + (size_t)cc * M + rr0) = o;
    }
}

// ---------- reduce split-K bf16 partials + bias + ReLU ----------
// thread: col c = idx>>7, rows r0..r0+7; coalesced short8 reads
__global__ __launch_bounds__(256) void k_epi1(const __hip_bfloat16* __restrict__ parts,
                                              const float* __restrict__ b1,
                                              float* __restrict__ h, int M) {
  int idx = blockIdx.x * 256 + threadIdx.x;     // 65536 total
  int c = idx >> 7;
  int r0 = (idx & 127) * 8;
  const unsigned short* base = (const unsigned short*)parts + (size_t)c * M + r0;
  float a[8] = {0.f, 0.f, 0.f, 0.f, 0.f, 0.f, 0.f, 0.f};
  for (int p = 0; p < SPLITK; ++p) {
    short8 v = *(const short8*)(base + (size_t)p * HID * M);
#pragma unroll
    for (int e = 0; e < 8; ++e) a[e] += bf2f((unsigned short)v[e]);
  }
  float bb = b1[c];
#pragma unroll
  for (int e = 0; e < 8; ++e)
    h[(size_t)(r0 + e) * HID + c] = fmaxf(a[e] + bb, 0.f);
}

// ---------- head: out = h @ W2 + b2, sigmoids, scatter ----------
__global__ __launch_bounds__(256) void k_head(const float* __restrict__ h,
                                              const float* __restrict__ W2,
                                              const float* __restrict__ b2,
                                              float* __restrict__ out, int N) {
  __shared__ float hrow[512];
  __shared__ float part[16][17];
  const int n = blockIdx.x, t = threadIdx.x;
  hrow[t]       = h[(size_t)n * HID + t];
  hrow[t + 256] = h[(size_t)n * HID + 256 + t];
  __syncthreads();
  int j = t & 15, kc = t >> 4;
  float a = 0.f;
  if (j < 11) {
#pragma unroll
    for (int kk = 0; kk < 32; ++kk) {
      int k = kc * 32 + kk;
      a += hrow[k] * W2[k * 11 + j];
    }
  }
  part[kc][j] = a;
  __syncthreads();
  if (t < 11) {
    float sm = b2[t];
#pragma unroll
    for (int k2 = 0; k2 < 16; ++k2) sm += part[k2][t];
    if (t == 0)      out[n] = 1.f / (1.f + expf(-sm));
    else if (t == 1) out[N + n] = 1.f / (1.f + expf(-sm));
    else if (t < 6)  out[2 * N + n * 4 + (t - 2)] = sm;
    else if (t < 10) out[6 * N + n * 4 + (t - 6)] = sm;
    else             out[10 * N + n] = 1.f / (1.f + expf(-sm));
  }
}

extern "C" void kernel_launch(void* const* d_in, const int* in_sizes, int n_in,
                              void* d_out, int out_size, void* d_ws, size_t ws_size,
                              hipStream_t stream) {
  const float* feats1 = (const float*)d_in[0];
  const float* feats2 = (const float*)d_in[1];
  const float* props  = (const float*)d_in[2];
  const float* W1     = (const float*)d_in[3];
  const float* b1     = (const float*)d_in[4];
  const float* W2     = (const float*)d_in[5];
  const float* b2     = (const float*)d_in[6];
  float* out = (float*)d_out;
  const int N = in_sizes[2] / 4;   // 1024

  char* ws = (char*)d_ws;
  __hip_bfloat16* ft = (__hip_bfloat16*)ws;                        // 1 MB
  __hip_bfloat16* Abuf = (__hip_bfloat16*)(ws + (1u << 20));       // 49 MB
  size_t offW1t = (1u << 20) + (size_t)N * KTOT * 2;
  __hip_bfloat16* W1t = (__hip_bfloat16*)(ws + offW1t);            // 24.5 MB
  size_t offParts = offW1t + (size_t)HID * KTOT * 2;
  __hip_bfloat16* parts = (__hip_bfloat16*)(ws + offParts);        // 28 MB (bf16, [sp][col][row])
  size_t offH = offParts + (size_t)SPLITK * N * HID * 2;
  float* h = (float*)(ws + offH);                                  // 2 MB

  k_tfeat<<<dim3(4, 16, 2), 256, 0, stream>>>(feats1, feats2, ft);
  k_tw1<<<dim3(32, 49, 2), 256, 0, stream>>>(W1, W1t);
  k_roi<<<dim3(N / 2, 7), 256, 0, stream>>>(ft, props, Abuf);
  k_gemm1<<<dim3(N / 128, HID / 128, SPLITK), 256, 0, stream>>>(Abuf, W1t, parts, N);
  k_epi1<<<dim3((N * HID) / 2048), 256, 0, stream>>>(parts, b1, h, N);
  k_head<<<dim3(N), 256, 0, stream>>>(h, W2, b2, out, N);
}

// Round 7
// 125.883 us; speedup vs baseline: 1.1270x; 1.1270x over previous
//
#include <hip/hip_runtime.h>
#include <hip/hip_bf16.h>

#define KTOT   25088          // 2 * 256 * 49
#define HALF_K 12544
#define HID    512
#define SPLITK 16
#define KCHUNK (KTOT/SPLITK)  // 1568
#define KSTEPS (KCHUNK/32)    // 49

typedef __attribute__((ext_vector_type(8))) short short8;
typedef __attribute__((ext_vector_type(4))) float f32x4;

__device__ __forceinline__ unsigned short f2bf(float x) {
  __hip_bfloat16 h = __float2bfloat16(x);
  return *reinterpret_cast<unsigned short*>(&h);
}
__device__ __forceinline__ float bf2f(unsigned short u) {
  return __uint_as_float((unsigned)u << 16);
}

// ---------- feats [C,H,W] fp32 -> ft bf16 [map][y*32+x][c] ----------
__global__ __launch_bounds__(256) void k_tfeat(const float* __restrict__ f1,
                                               const float* __restrict__ f2,
                                               __hip_bfloat16* __restrict__ ft) {
  __shared__ float tile[64][65];
  const int ct = blockIdx.x, yxt = blockIdx.y, map = blockIdx.z;
  const float* src = map ? f2 : f1;
  const int t = threadIdx.x, t4 = t >> 6, tl = t & 63;
#pragma unroll
  for (int pass = 0; pass < 16; ++pass) {
    int cl = pass * 4 + t4;
    tile[cl][tl] = src[(ct * 64 + cl) * 1024 + yxt * 64 + tl];
  }
  __syncthreads();
#pragma unroll
  for (int pass = 0; pass < 16; ++pass) {
    int yl = pass * 4 + t4;
    ft[(size_t)map * 262144 + (size_t)(yxt * 64 + yl) * 256 + ct * 64 + tl] =
        __float2bfloat16(tile[tl][yl]);
  }
}

// ---------- W1 [25088][512] -> W1t bf16 [512][25088'] with k' = map*12544 + p*256 + c ----------
__global__ __launch_bounds__(256) void k_tw1(const float* __restrict__ W1,
                                             __hip_bfloat16* __restrict__ W1t) {
  __shared__ float tile[64][65];
  const int ct = blockIdx.x & 3, jt = blockIdx.x >> 2;
  const int p = blockIdx.y, map = blockIdx.z;
  const int t = threadIdx.x, t4 = t >> 6, tl = t & 63;
#pragma unroll
  for (int pass = 0; pass < 16; ++pass) {
    int cl = pass * 4 + t4;
    int c = ct * 64 + cl;
    size_t krow = (size_t)map * HALF_K + (size_t)c * 49 + p;
    tile[cl][tl] = W1[krow * HID + jt * 64 + tl];
  }
  __syncthreads();
#pragma unroll
  for (int pass = 0; pass < 16; ++pass) {
    int jl = pass * 4 + t4;
    int j = jt * 64 + jl;
    W1t[(size_t)j * KTOT + (size_t)map * HALF_K + p * 256 + ct * 64 + tl] =
        __float2bfloat16(tile[tl][jl]);
  }
}

// ---------- RoIAlign: 7-way bin-row split, b128 table reads, 32-bit offsets ----------
// grid (N/2, 7); t: b=t>>7, map=(t>>6)&1, q=t&63 -> channels q*4..q*4+3
__global__ __launch_bounds__(256) void k_roi(const __hip_bfloat16* __restrict__ ft,
                                             const float* __restrict__ props,
                                             __hip_bfloat16* __restrict__ A) {
  __shared__ __align__(16) int2 tab[2][7 * 16];  // [box][bin_local*16 + sample*4 + corner]
  const int t = threadIdx.x;
  const int nb = blockIdx.x * 2;
  const int bin0 = blockIdx.y * 7;
  const float sc = 1.0f / 32.0f;
  for (int e = t; e < 224; e += 256) {
    int b = (e >= 112) ? 1 : 0;
    int ei = e - b * 112;
    int bin = bin0 + (ei >> 4), k = ei & 15;
    int s = k >> 2, corner = k & 3;
    int oyb = bin / 7, oxb = bin - oyb * 7;
    int py = oyb * 2 + (s >> 1), px = oxb * 2 + (s & 1);
    int n = nb + b;
    float bx1 = props[n * 4 + 0] * sc, by1 = props[n * 4 + 1] * sc;
    float bx2 = props[n * 4 + 2] * sc, by2 = props[n * 4 + 3] * sc;
    float bw = fmaxf(bx2 - bx1, 1.f) * (1.f / 7.f);
    float bh = fmaxf(by2 - by1, 1.f) * (1.f / 7.f);
    float oxf = bx1 + (float)(px >> 1) * bw + ((float)(px & 1) + 0.5f) * bw * 0.5f;
    float oyf = by1 + (float)(py >> 1) * bh + ((float)(py & 1) + 0.5f) * bh * 0.5f;
    float vx = (oxf >= -1.f && oxf <= 32.f) ? 1.f : 0.f;
    float vy = (oyf >= -1.f && oyf <= 32.f) ? 1.f : 0.f;
    float ocx = fminf(fmaxf(oxf, 0.f), 31.f);
    float ocy = fminf(fmaxf(oyf, 0.f), 31.f);
    int x0 = (int)ocx, y0 = (int)ocy;
    int x1 = min(x0 + 1, 31), y1 = min(y0 + 1, 31);
    float lx = ocx - (float)x0, ly = ocy - (float)y0;
    int cy = corner >> 1, cx = corner & 1;
    int yi = cy ? y1 : y0, xi = cx ? x1 : x0;
    float wyc = cy ? ly : (1.f - ly);
    float wxc = cx ? lx : (1.f - lx);
    float w = vx * vy * 0.25f * wyc * wxc;
    int2 v; v.x = (yi * 32 + xi) * 512; v.y = __float_as_int(w);
    tab[b][ei] = v;
  }
  __syncthreads();
  const int b = t >> 7, map = (t >> 6) & 1, q = t & 63;
  const char* fb = (const char*)ft;
  const unsigned qoff = (unsigned)(map * 524288 + q * 8);
  const int n = nb + b;
  __hip_bfloat16* outp = A + (size_t)n * KTOT + map * HALF_K + q * 4;
  const int4* tb = (const int4*)&tab[b][0];
  for (int bl = 0; bl < 7; ++bl) {
    float a0 = 0.f, a1 = 0.f, a2 = 0.f, a3 = 0.f;
#pragma unroll
    for (int k2 = 0; k2 < 8; ++k2) {
      int4 ow = tb[bl * 8 + k2];
      unsigned o0 = qoff + (unsigned)ow.x;
      float w0 = __int_as_float(ow.y);
      ushort4 u0 = *(const ushort4*)(fb + o0);
      unsigned o1 = qoff + (unsigned)ow.z;
      float w1 = __int_as_float(ow.w);
      ushort4 u1 = *(const ushort4*)(fb + o1);
      a0 += w0 * bf2f(u0.x); a1 += w0 * bf2f(u0.y);
      a2 += w0 * bf2f(u0.z); a3 += w0 * bf2f(u0.w);
      a0 += w1 * bf2f(u1.x); a1 += w1 * bf2f(u1.y);
      a2 += w1 * bf2f(u1.z); a3 += w1 * bf2f(u1.w);
    }
    ushort4 o;
    o.x = f2bf(a0); o.y = f2bf(a1); o.z = f2bf(a2); o.w = f2bf(a3);
    *(ushort4*)(outp + (bin0 + bl) * 256) = o;
  }
}

// ---------- GEMM1: m97 structure, 128x128 tile, BK=32, 4 waves, XCD-chunked swizzle ----------
__device__ __forceinline__ void gl_lds16(const __hip_bfloat16* g, __hip_bfloat16* l) {
  __builtin_amdgcn_global_load_lds((const __attribute__((address_space(1))) void*)g,
                                   (__attribute__((address_space(3))) void*)l, 16, 0, 0);
}

__global__ __launch_bounds__(256) void k_gemm1(const __hip_bfloat16* __restrict__ A,
                                               const __hip_bfloat16* __restrict__ Bt,
                                               float* __restrict__ parts, int M) {
  __shared__ __align__(16) __hip_bfloat16 As[128 * 32];
  __shared__ __align__(16) __hip_bfloat16 Bs[128 * 32];
  const int t = threadIdx.x;
  // XCD-chunked swizzle: 512 blocks, 8 XCDs, 64 blocks/XCD contiguous.
  // chunk of 64 new-ids = all 8 row-tiles x 4 col-tiles x 2 k-chunks -> A,B sharing intra-XCD
  const int bid = blockIdx.x + 8 * (blockIdx.y + 4 * blockIdx.z);
  const int swz = (bid & 7) * 64 + (bid >> 3);
  const int bx = swz & 7, by = (swz >> 3) & 3, bz = swz >> 5;
  const int row0 = bx * 128, col0 = by * 128;
  const size_t k0 = (size_t)bz * KCHUNK;
  const int lr = t >> 2, lg = t & 3;
  const int sg = lg ^ ((lr >> 1) & 3);
  const __hip_bfloat16* ag0 = A  + (size_t)(row0 + lr) * KTOT + k0 + sg * 8;
  const __hip_bfloat16* ag1 = A  + (size_t)(row0 + 64 + lr) * KTOT + k0 + sg * 8;
  const __hip_bfloat16* bg0 = Bt + (size_t)(col0 + lr) * KTOT + k0 + sg * 8;
  const __hip_bfloat16* bg1 = Bt + (size_t)(col0 + 64 + lr) * KTOT + k0 + sg * 8;
  __hip_bfloat16* la0 = &As[t * 8];
  __hip_bfloat16* la1 = &As[2048 + t * 8];
  __hip_bfloat16* lb0 = &Bs[t * 8];
  __hip_bfloat16* lb1 = &Bs[2048 + t * 8];

  const int lane = t & 63, w = t >> 6;
  const int wr = (w >> 1) * 64, wc = (w & 1) * 64;
  const int r = lane & 15, g = lane >> 4;
  const int s = g ^ ((r >> 1) & 3);
  const int iab = (wr + r) * 32 + s * 8;
  const int ibb = (wc + r) * 32 + s * 8;

  f32x4 acc[4][4];
#pragma unroll
  for (int m = 0; m < 4; ++m)
#pragma unroll
    for (int n = 0; n < 4; ++n) acc[m][n] = (f32x4){0.f, 0.f, 0.f, 0.f};

  for (int kt = 0; kt < KSTEPS; ++kt) {
    gl_lds16(ag0, la0); gl_lds16(ag1, la1);
    gl_lds16(bg0, lb0); gl_lds16(bg1, lb1);
    ag0 += 32; ag1 += 32; bg0 += 32; bg1 += 32;
    __syncthreads();
    short8 af[4], bfr[4];
#pragma unroll
    for (int m = 0; m < 4; ++m) af[m] = *(const short8*)&As[iab + m * 512];
#pragma unroll
    for (int n = 0; n < 4; ++n) bfr[n] = *(const short8*)&Bs[ibb + n * 512];
#pragma unroll
    for (int m = 0; m < 4; ++m)
#pragma unroll
      for (int n = 0; n < 4; ++n)
        acc[m][n] = __builtin_amdgcn_mfma_f32_16x16x32_bf16(af[m], bfr[n], acc[m][n], 0, 0, 0);
    __syncthreads();
  }
  float* P = parts + (size_t)bz * ((size_t)M * HID);
#pragma unroll
  for (int m = 0; m < 4; ++m)
#pragma unroll
    for (int n = 0; n < 4; ++n)
#pragma unroll
      for (int q = 0; q < 4; ++q) {
        int rr = row0 + wr + m * 16 + g * 4 + q;
        int cc = col0 + wc + n * 16 + r;
        P[(size_t)rr * HID + cc] = acc[m][n][q];
      }
}

// ---------- reduce split-K partials + bias + ReLU (float4) ----------
__global__ __launch_bounds__(256) void k_epi1(const float4* __restrict__ parts,
                                              const float4* __restrict__ b1,
                                              float4* __restrict__ h, int M) {
  int idx = blockIdx.x * 256 + threadIdx.x;       // float4 index
  size_t stride = (size_t)M * (HID / 4);
  float4 s = b1[idx & (HID / 4 - 1)];
#pragma unroll
  for (int p = 0; p < SPLITK; ++p) {
    float4 v = parts[idx + (size_t)p * stride];
    s.x += v.x; s.y += v.y; s.z += v.z; s.w += v.w;
  }
  s.x = fmaxf(s.x, 0.f); s.y = fmaxf(s.y, 0.f);
  s.z = fmaxf(s.z, 0.f); s.w = fmaxf(s.w, 0.f);
  h[idx] = s;
}

// ---------- head: out = h @ W2 + b2, sigmoids, scatter ----------
__global__ __launch_bounds__(256) void k_head(const float* __restrict__ h,
                                              const float* __restrict__ W2,
                                              const float* __restrict__ b2,
                                              float* __restrict__ out, int N) {
  __shared__ float hrow[512];
  __shared__ float part[16][17];
  const int n = blockIdx.x, t = threadIdx.x;
  hrow[t]       = h[(size_t)n * HID + t];
  hrow[t + 256] = h[(size_t)n * HID + 256 + t];
  __syncthreads();
  int j = t & 15, kc = t >> 4;
  float a = 0.f;
  if (j < 11) {
#pragma unroll
    for (int kk = 0; kk < 32; ++kk) {
      int k = kc * 32 + kk;
      a += hrow[k] * W2[k * 11 + j];
    }
  }
  part[kc][j] = a;
  __syncthreads();
  if (t < 11) {
    float sm = b2[t];
#pragma unroll
    for (int k2 = 0; k2 < 16; ++k2) sm += part[k2][t];
    if (t == 0)      out[n] = 1.f / (1.f + expf(-sm));
    else if (t == 1) out[N + n] = 1.f / (1.f + expf(-sm));
    else if (t < 6)  out[2 * N + n * 4 + (t - 2)] = sm;
    else if (t < 10) out[6 * N + n * 4 + (t - 6)] = sm;
    else             out[10 * N + n] = 1.f / (1.f + expf(-sm));
  }
}

extern "C" void kernel_launch(void* const* d_in, const int* in_sizes, int n_in,
                              void* d_out, int out_size, void* d_ws, size_t ws_size,
                              hipStream_t stream) {
  const float* feats1 = (const float*)d_in[0];
  const float* feats2 = (const float*)d_in[1];
  const float* props  = (const float*)d_in[2];
  const float* W1     = (const float*)d_in[3];
  const float* b1     = (const float*)d_in[4];
  const float* W2     = (const float*)d_in[5];
  const float* b2     = (const float*)d_in[6];
  float* out = (float*)d_out;
  const int N = in_sizes[2] / 4;   // 1024

  char* ws = (char*)d_ws;
  __hip_bfloat16* ft = (__hip_bfloat16*)ws;                        // 1 MB
  __hip_bfloat16* Abuf = (__hip_bfloat16*)(ws + (1u << 20));       // 49 MB
  size_t offW1t = (1u << 20) + (size_t)N * KTOT * 2;
  __hip_bfloat16* W1t = (__hip_bfloat16*)(ws + offW1t);            // 24.5 MB
  size_t offParts = offW1t + (size_t)HID * KTOT * 2;
  float* parts = (float*)(ws + offParts);                          // 32 MB
  size_t offH = offParts + (size_t)SPLITK * N * HID * 4;
  float* h = (float*)(ws + offH);                                  // 2 MB

  k_tfeat<<<dim3(4, 16, 2), 256, 0, stream>>>(feats1, feats2, ft);
  k_tw1<<<dim3(32, 49, 2), 256, 0, stream>>>(W1, W1t);
  k_roi<<<dim3(N / 2, 7), 256, 0, stream>>>(ft, props, Abuf);
  k_gemm1<<<dim3(8, 4, SPLITK), 256, 0, stream>>>(Abuf, W1t, parts, N);
  k_epi1<<<dim3((N * HID) / 1024), 256, 0, stream>>>((const float4*)parts,
                                                     (const float4*)b1, (float4*)h, N);
  k_head<<<dim3(N), 256, 0, stream>>>(h, W2, b2, out, N);
}

// Round 8
// 108.328 us; speedup vs baseline: 1.3096x; 1.1621x over previous
//
#include <hip/hip_runtime.h>
#include <hip/hip_bf16.h>

#define KTOT   25088          // 2 * 256 * 49
#define HALF_K 12544
#define HID    512
#define SPLITK 16
#define KCHUNK (KTOT/SPLITK)  // 1568
#define KSTEPS (KCHUNK/32)    // 49

typedef __attribute__((ext_vector_type(8))) short short8;
typedef __attribute__((ext_vector_type(4))) float f32x4;

__device__ __forceinline__ unsigned short f2bf(float x) {
  __hip_bfloat16 h = __float2bfloat16(x);
  return *reinterpret_cast<unsigned short*>(&h);
}
__device__ __forceinline__ float bf2f(unsigned short u) {
  return __uint_as_float((unsigned)u << 16);
}

// ---------- feats [C,H,W] fp32 -> ft bf16 [map][y*32+x][c] ----------
__global__ __launch_bounds__(256) void k_tfeat(const float* __restrict__ f1,
                                               const float* __restrict__ f2,
                                               __hip_bfloat16* __restrict__ ft) {
  __shared__ float tile[64][65];
  const int ct = blockIdx.x, yxt = blockIdx.y, map = blockIdx.z;
  const float* src = map ? f2 : f1;
  const int t = threadIdx.x, t4 = t >> 6, tl = t & 63;
#pragma unroll
  for (int pass = 0; pass < 16; ++pass) {
    int cl = pass * 4 + t4;
    tile[cl][tl] = src[(ct * 64 + cl) * 1024 + yxt * 64 + tl];
  }
  __syncthreads();
#pragma unroll
  for (int pass = 0; pass < 16; ++pass) {
    int yl = pass * 4 + t4;
    ft[(size_t)map * 262144 + (size_t)(yxt * 64 + yl) * 256 + ct * 64 + tl] =
        __float2bfloat16(tile[tl][yl]);
  }
}

// ---------- W1 [25088][512] -> W1t bf16 [512][25088'] with k' = map*12544 + p*256 + c ----------
__global__ __launch_bounds__(256) void k_tw1(const float* __restrict__ W1,
                                             __hip_bfloat16* __restrict__ W1t) {
  __shared__ float tile[64][65];
  const int ct = blockIdx.x & 3, jt = blockIdx.x >> 2;
  const int p = blockIdx.y, map = blockIdx.z;
  const int t = threadIdx.x, t4 = t >> 6, tl = t & 63;
#pragma unroll
  for (int pass = 0; pass < 16; ++pass) {
    int cl = pass * 4 + t4;
    int c = ct * 64 + cl;
    size_t krow = (size_t)map * HALF_K + (size_t)c * 49 + p;
    tile[cl][tl] = W1[krow * HID + jt * 64 + tl];
  }
  __syncthreads();
#pragma unroll
  for (int pass = 0; pass < 16; ++pass) {
    int jl = pass * 4 + t4;
    int j = jt * 64 + jl;
    W1t[(size_t)j * KTOT + (size_t)map * HALF_K + p * 256 + ct * 64 + tl] =
        __float2bfloat16(tile[tl][jl]);
  }
}

// ---------- RoIAlign: separable merged-corner gather ----------
// grid (N/2, 7): blockIdx.y = output row oy; per block: 2 boxes.
// Per box: 1 y-axis table (shared by 7 bins) + 7 x-axis tables, each <=4 merged (off,w).
// bin = sum_yy sum_xx WY*WX*F[yy,xx]  (subsample grid is tensor-product => separable)
__global__ __launch_bounds__(256) void k_roi(const __hip_bfloat16* __restrict__ ft,
                                             const float* __restrict__ props,
                                             __hip_bfloat16* __restrict__ A) {
  __shared__ int   s_ny[2];
  __shared__ int   s_yoff[2][4];
  __shared__ float s_wy[2][4];
  __shared__ int   s_nx[2][7];
  __shared__ int   s_xoff[2][7][4];
  __shared__ float s_wx[2][7][4];
  const int t = threadIdx.x;
  const int nb = blockIdx.x * 2;
  const int oy = blockIdx.y;
  const float sc = 1.0f / 32.0f;
  if (t < 16) {
    const int b = t & 1, j = t >> 1;          // j==0: y-axis; j-1 = ox for x-axis
    const int n = nb + b;
    float bx1 = props[n * 4 + 0] * sc, by1 = props[n * 4 + 1] * sc;
    float bx2 = props[n * 4 + 2] * sc, by2 = props[n * 4 + 3] * sc;
    float bw = fmaxf(bx2 - bx1, 1.f) * (1.f / 7.f);
    float bh = fmaxf(by2 - by1, 1.f) * (1.f / 7.f);
    const bool isY = (j == 0);
    const int i = isY ? oy : (j - 1);
    const float start = isY ? by1 : bx1;
    const float bs = isY ? bh : bw;
    int idxs[4]; float ws[4];
#pragma unroll
    for (int ssub = 0; ssub < 2; ++ssub) {
      float o = start + (float)i * bs + ((float)ssub + 0.5f) * bs * 0.5f;
      float v = (o >= -1.f && o <= 32.f) ? 1.f : 0.f;
      float oc = fminf(fmaxf(o, 0.f), 31.f);
      int i0 = (int)oc;
      int i1 = min(i0 + 1, 31);
      float l = oc - (float)i0;
      idxs[ssub * 2 + 0] = i0; ws[ssub * 2 + 0] = v * (1.f - l);
      idxs[ssub * 2 + 1] = i1; ws[ssub * 2 + 1] = v * l;
    }
    int mi[4]; float mw[4]; int cnt = 0;
#pragma unroll
    for (int e = 0; e < 4; ++e) {
      if (ws[e] != 0.f) {
        bool found = false;
#pragma unroll
        for (int f = 0; f < 4; ++f)
          if (f < cnt && mi[f] == idxs[e]) { mw[f] += ws[e]; found = true; }
        if (!found) { mi[cnt] = idxs[e]; mw[cnt] = ws[e]; ++cnt; }
      }
    }
#pragma unroll
    for (int f = 0; f < 4; ++f) if (f >= cnt) { mi[f] = 0; mw[f] = 0.f; }
    if (isY) {
      s_ny[b] = cnt;
#pragma unroll
      for (int f = 0; f < 4; ++f) { s_yoff[b][f] = mi[f] * 16384; s_wy[b][f] = mw[f] * 0.25f; }
    } else {
      s_nx[b][j - 1] = cnt;
#pragma unroll
      for (int f = 0; f < 4; ++f) { s_xoff[b][j - 1][f] = mi[f] * 512; s_wx[b][j - 1][f] = mw[f]; }
    }
  }
  __syncthreads();
  const int b = t >> 7, map = (t >> 6) & 1, q = t & 63;
  const char* fb = (const char*)ft;
  const unsigned qoff = (unsigned)(map * 524288 + q * 8);
  const int n = nb + b;
  const int ny = s_ny[b];
  unsigned ybase[4]; float wyr[4];
#pragma unroll
  for (int yy = 0; yy < 4; ++yy) {
    ybase[yy] = qoff + (unsigned)s_yoff[b][yy];
    wyr[yy] = s_wy[b][yy];
  }
  __hip_bfloat16* outp = A + (size_t)n * KTOT + map * HALF_K + q * 4 + oy * 7 * 256;
  for (int bl = 0; bl < 7; ++bl) {
    const int nx = s_nx[b][bl];
    float a0 = 0.f, a1 = 0.f, a2 = 0.f, a3 = 0.f;
    for (int xx = 0; xx < nx; ++xx) {
      const unsigned xo = (unsigned)s_xoff[b][bl][xx];
      const float wxv = s_wx[b][bl][xx];
      for (int yy = 0; yy < ny; ++yy) {
        ushort4 u = *(const ushort4*)(fb + (ybase[yy] + xo));
        float w = wyr[yy] * wxv;
        a0 += w * bf2f(u.x); a1 += w * bf2f(u.y);
        a2 += w * bf2f(u.z); a3 += w * bf2f(u.w);
      }
    }
    ushort4 o;
    o.x = f2bf(a0); o.y = f2bf(a1); o.z = f2bf(a2); o.w = f2bf(a3);
    *(ushort4*)(outp + bl * 256) = o;
  }
}

// ---------- GEMM1: m97 structure, 128x128 tile, BK=32, 4 waves, XCD-chunked swizzle ----------
__device__ __forceinline__ void gl_lds16(const __hip_bfloat16* g, __hip_bfloat16* l) {
  __builtin_amdgcn_global_load_lds((const __attribute__((address_space(1))) void*)g,
                                   (__attribute__((address_space(3))) void*)l, 16, 0, 0);
}

__global__ __launch_bounds__(256) void k_gemm1(const __hip_bfloat16* __restrict__ A,
                                               const __hip_bfloat16* __restrict__ Bt,
                                               float* __restrict__ parts, int M) {
  __shared__ __align__(16) __hip_bfloat16 As[128 * 32];
  __shared__ __align__(16) __hip_bfloat16 Bs[128 * 32];
  const int t = threadIdx.x;
  const int bid = blockIdx.x + 8 * (blockIdx.y + 4 * blockIdx.z);
  const int swz = (bid & 7) * 64 + (bid >> 3);
  const int bx = swz & 7, by = (swz >> 3) & 3, bz = swz >> 5;
  const int row0 = bx * 128, col0 = by * 128;
  const size_t k0 = (size_t)bz * KCHUNK;
  const int lr = t >> 2, lg = t & 3;
  const int sg = lg ^ ((lr >> 1) & 3);
  const __hip_bfloat16* ag0 = A  + (size_t)(row0 + lr) * KTOT + k0 + sg * 8;
  const __hip_bfloat16* ag1 = A  + (size_t)(row0 + 64 + lr) * KTOT + k0 + sg * 8;
  const __hip_bfloat16* bg0 = Bt + (size_t)(col0 + lr) * KTOT + k0 + sg * 8;
  const __hip_bfloat16* bg1 = Bt + (size_t)(col0 + 64 + lr) * KTOT + k0 + sg * 8;
  __hip_bfloat16* la0 = &As[t * 8];
  __hip_bfloat16* la1 = &As[2048 + t * 8];
  __hip_bfloat16* lb0 = &Bs[t * 8];
  __hip_bfloat16* lb1 = &Bs[2048 + t * 8];

  const int lane = t & 63, w = t >> 6;
  const int wr = (w >> 1) * 64, wc = (w & 1) * 64;
  const int r = lane & 15, g = lane >> 4;
  const int s = g ^ ((r >> 1) & 3);
  const int iab = (wr + r) * 32 + s * 8;
  const int ibb = (wc + r) * 32 + s * 8;

  f32x4 acc[4][4];
#pragma unroll
  for (int m = 0; m < 4; ++m)
#pragma unroll
    for (int n = 0; n < 4; ++n) acc[m][n] = (f32x4){0.f, 0.f, 0.f, 0.f};

  for (int kt = 0; kt < KSTEPS; ++kt) {
    gl_lds16(ag0, la0); gl_lds16(ag1, la1);
    gl_lds16(bg0, lb0); gl_lds16(bg1, lb1);
    ag0 += 32; ag1 += 32; bg0 += 32; bg1 += 32;
    __syncthreads();
    short8 af[4], bfr[4];
#pragma unroll
    for (int m = 0; m < 4; ++m) af[m] = *(const short8*)&As[iab + m * 512];
#pragma unroll
    for (int n = 0; n < 4; ++n) bfr[n] = *(const short8*)&Bs[ibb + n * 512];
#pragma unroll
    for (int m = 0; m < 4; ++m)
#pragma unroll
      for (int n = 0; n < 4; ++n)
        acc[m][n] = __builtin_amdgcn_mfma_f32_16x16x32_bf16(af[m], bfr[n], acc[m][n], 0, 0, 0);
    __syncthreads();
  }
  float* P = parts + (size_t)bz * ((size_t)M * HID);
#pragma unroll
  for (int m = 0; m < 4; ++m)
#pragma unroll
    for (int n = 0; n < 4; ++n)
#pragma unroll
      for (int q = 0; q < 4; ++q) {
        int rr = row0 + wr + m * 16 + g * 4 + q;
        int cc = col0 + wc + n * 16 + r;
        P[(size_t)rr * HID + cc] = acc[m][n][q];
      }
}

// ---------- reduce split-K partials + bias + ReLU (float4) ----------
__global__ __launch_bounds__(256) void k_epi1(const float4* __restrict__ parts,
                                              const float4* __restrict__ b1,
                                              float4* __restrict__ h, int M) {
  int idx = blockIdx.x * 256 + threadIdx.x;       // float4 index
  size_t stride = (size_t)M * (HID / 4);
  float4 s = b1[idx & (HID / 4 - 1)];
#pragma unroll
  for (int p = 0; p < SPLITK; ++p) {
    float4 v = parts[idx + (size_t)p * stride];
    s.x += v.x; s.y += v.y; s.z += v.z; s.w += v.w;
  }
  s.x = fmaxf(s.x, 0.f); s.y = fmaxf(s.y, 0.f);
  s.z = fmaxf(s.z, 0.f); s.w = fmaxf(s.w, 0.f);
  h[idx] = s;
}

// ---------- head: out = h @ W2 + b2, sigmoids, scatter ----------
__global__ __launch_bounds__(256) void k_head(const float* __restrict__ h,
                                              const float* __restrict__ W2,
                                              const float* __restrict__ b2,
                                              float* __restrict__ out, int N) {
  __shared__ float hrow[512];
  __shared__ float part[16][17];
  const int n = blockIdx.x, t = threadIdx.x;
  hrow[t]       = h[(size_t)n * HID + t];
  hrow[t + 256] = h[(size_t)n * HID + 256 + t];
  __syncthreads();
  int j = t & 15, kc = t >> 4;
  float a = 0.f;
  if (j < 11) {
#pragma unroll
    for (int kk = 0; kk < 32; ++kk) {
      int k = kc * 32 + kk;
      a += hrow[k] * W2[k * 11 + j];
    }
  }
  part[kc][j] = a;
  __syncthreads();
  if (t < 11) {
    float sm = b2[t];
#pragma unroll
    for (int k2 = 0; k2 < 16; ++k2) sm += part[k2][t];
    if (t == 0)      out[n] = 1.f / (1.f + expf(-sm));
    else if (t == 1) out[N + n] = 1.f / (1.f + expf(-sm));
    else if (t < 6)  out[2 * N + n * 4 + (t - 2)] = sm;
    else if (t < 10) out[6 * N + n * 4 + (t - 6)] = sm;
    else             out[10 * N + n] = 1.f / (1.f + expf(-sm));
  }
}

extern "C" void kernel_launch(void* const* d_in, const int* in_sizes, int n_in,
                              void* d_out, int out_size, void* d_ws, size_t ws_size,
                              hipStream_t stream) {
  const float* feats1 = (const float*)d_in[0];
  const float* feats2 = (const float*)d_in[1];
  const float* props  = (const float*)d_in[2];
  const float* W1     = (const float*)d_in[3];
  const float* b1     = (const float*)d_in[4];
  const float* W2     = (const float*)d_in[5];
  const float* b2     = (const float*)d_in[6];
  float* out = (float*)d_out;
  const int N = in_sizes[2] / 4;   // 1024

  char* ws = (char*)d_ws;
  __hip_bfloat16* ft = (__hip_bfloat16*)ws;                        // 1 MB
  __hip_bfloat16* Abuf = (__hip_bfloat16*)(ws + (1u << 20));       // 49 MB
  size_t offW1t = (1u << 20) + (size_t)N * KTOT * 2;
  __hip_bfloat16* W1t = (__hip_bfloat16*)(ws + offW1t);            // 24.5 MB
  size_t offParts = offW1t + (size_t)HID * KTOT * 2;
  float* parts = (float*)(ws + offParts);                          // 32 MB
  size_t offH = offParts + (size_t)SPLITK * N * HID * 4;
  float* h = (float*)(ws + offH);                                  // 2 MB

  k_tfeat<<<dim3(4, 16, 2), 256, 0, stream>>>(feats1, feats2, ft);
  k_tw1<<<dim3(32, 49, 2), 256, 0, stream>>>(W1, W1t);
  k_roi<<<dim3(N / 2, 7), 256, 0, stream>>>(ft, props, Abuf);
  k_gemm1<<<dim3(8, 4, SPLITK), 256, 0, stream>>>(Abuf, W1t, parts, N);
  k_epi1<<<dim3((N * HID) / 1024), 256, 0, stream>>>((const float4*)parts,
                                                     (const float4*)b1, (float4*)h, N);
  k_head<<<dim3(N), 256, 0, stream>>>(h, W2, b2, out, N);
}